// Round 5
// baseline (587.784 us; speedup 1.0000x reference)
//
#include <hip/hip_runtime.h>

#define NN 100000
#define EE 1600000
#define DD 128
#define LL 3

typedef float f32x4 __attribute__((ext_vector_type(4)));
typedef _Float16 f16x8 __attribute__((ext_vector_type(8)));
typedef unsigned short u16;
typedef unsigned int u32;
typedef u16 u16x8 __attribute__((ext_vector_type(8)));

// CSR-build geometry: buckets of 256 nodes, chunks of 16384 edges
#define NBUCK ((NN + 255) / 256)          // 391
#define CHUNK 16384
#define NCHUNK ((EE + CHUNK - 1) / CHUNK) // 98

__device__ __forceinline__ u16 f2h_bits(float f) {
    _Float16 h = (_Float16)f;
    return __builtin_bit_cast(u16, h);
}
__device__ __forceinline__ float2 h2f2(u32 v) {
    _Float16 lo = __builtin_bit_cast(_Float16, (u16)(v & 0xffff));
    _Float16 hi = __builtin_bit_cast(_Float16, (u16)(v >> 16));
    return make_float2((float)lo, (float)hi);
}
__device__ __forceinline__ u32 f22h(float x, float y) {
    return (u32)f2h_bits(x) | ((u32)f2h_bits(y) << 16);
}

// ---------------- CSR build: bucketed counting sort by dst ----------------

__global__ __launch_bounds__(1024) void csr_hist(const int* __restrict__ dst,
                                                 int* __restrict__ hist_g) {
    __shared__ int h[NBUCK];
    int t = threadIdx.x, c = blockIdx.x;
    for (int i = t; i < NBUCK; i += 1024) h[i] = 0;
    __syncthreads();
    int base = c * CHUNK;
    #pragma unroll
    for (int i = 0; i < CHUNK / 1024; ++i) {
        int e = base + t + i * 1024;
        if (e < EE) atomicAdd(&h[dst[e] >> 8], 1);
    }
    __syncthreads();
    for (int i = t; i < NBUCK; i += 1024) hist_g[i * NCHUNK + c] = h[i];
}

__global__ __launch_bounds__(512) void csr_scan(int* __restrict__ hist_g,
                                                int* __restrict__ bbase) {
    __shared__ int tot[512];
    int t = threadIdx.x;
    int sum = 0;
    if (t < NBUCK) {
        int* p = hist_g + t * NCHUNK;
        for (int c = 0; c < NCHUNK; ++c) { int v = p[c]; p[c] = sum; sum += v; }
    }
    tot[t] = sum; __syncthreads();
    for (int off = 1; off < 512; off <<= 1) {
        int u = (t >= off) ? tot[t - off] : 0;
        __syncthreads();
        tot[t] += u;
        __syncthreads();
    }
    int base = tot[t] - sum;   // exclusive
    if (t < NBUCK) {
        bbase[t] = base;
        int* p = hist_g + t * NCHUNK;
        for (int c = 0; c < NCHUNK; ++c) p[c] += base;
    }
    if (t == 0) bbase[NBUCK] = EE;
}

__global__ __launch_bounds__(1024) void csr_scatter(const int* __restrict__ src,
                                                    const int* __restrict__ dst,
                                                    const int* __restrict__ hist_g,
                                                    u32* __restrict__ rec) {
    __shared__ int cur[NBUCK];
    int t = threadIdx.x, c = blockIdx.x;
    for (int i = t; i < NBUCK; i += 1024) cur[i] = hist_g[i * NCHUNK + c];
    __syncthreads();
    int base = c * CHUNK;
    #pragma unroll
    for (int i = 0; i < CHUNK / 1024; ++i) {
        int e = base + t + i * 1024;
        if (e < EE) {
            int d = dst[e];
            int slot = atomicAdd(&cur[d >> 8], 1);
            rec[slot] = (u32)src[e] | ((u32)(d & 255) << 17);
        }
    }
}

__global__ __launch_bounds__(256) void csr_finalize(const u32* __restrict__ rec,
                                                    const int* __restrict__ bbase,
                                                    int* __restrict__ row_ptr,
                                                    int* __restrict__ col) {
    __shared__ int cur[256];
    __shared__ int sc[256];
    int b = blockIdx.x, t = threadIdx.x;
    int base = bbase[b], tot = bbase[b + 1] - base;
    sc[t] = 0; __syncthreads();
    for (int r = t; r < tot; r += 256) atomicAdd(&sc[rec[base + r] >> 17], 1);
    __syncthreads();
    int v = sc[t];
    for (int off = 1; off < 256; off <<= 1) {
        int u = (t >= off) ? sc[t - off] : 0;
        __syncthreads();
        sc[t] += u;
        __syncthreads();
    }
    int excl = sc[t] - v;
    cur[t] = excl;
    int nid = b * 256 + t;
    if (nid <= NN) row_ptr[nid] = base + excl;
    __syncthreads();
    for (int r = t; r < tot; r += 256) {
        u32 rc = rec[base + r];
        int slot = atomicAdd(&cur[rc >> 17], 1);
        col[base + slot] = (int)(rc & 0x1FFFFu);
    }
}

// ---------------- x (fp32) -> h16 ----------------

__global__ void cvt_kernel(const float* __restrict__ x, u32* __restrict__ h) {
    int i = blockIdx.x * blockDim.x + threadIdx.x;
    if (i < NN * 32) {
        float4 v = ((const float4*)x)[i];
        h[i * 2]     = f22h(v.x, v.y);
        h[i * 2 + 1] = f22h(v.z, v.w);
    }
}

// ---------------- fused layer: agg + MLP + LayerNorm + ReLU ----------------
// block = 256 threads = 4 waves; M-tile = 64 rows; wave w owns rows w*16..w*16+15.
// LDS: [0,32768)      W transposed (c-major) fp16, XOR-swizzled, W1 then W2 (phased)
//      [32768,49152)  z-tile (gather result), then REUSED as hidden transpose buffer.
// All z/hidden rows are wave-private -> only W staging needs barriers.

__device__ __forceinline__ void stage_w(const float* __restrict__ W, unsigned char* lds, int tid) {
    #pragma unroll
    for (int i = 0; i < 8; ++i) {
        int p = tid + i * 256;
        int c = p & 127;
        int k0 = (p >> 7) << 3;
        u16x8 t;
        #pragma unroll
        for (int j = 0; j < 8; ++j) t[j] = f2h_bits(W[(k0 + j) * 128 + c]);
        u32 off = ((((u32)c << 7) + k0) << 1) ^ (((u32)c & 7) << 4);
        *(u16x8*)(lds + off) = t;
    }
}

__global__ __launch_bounds__(256) void layer_kernel(
    const u32* __restrict__ h, const int* __restrict__ row_ptr,
    const int* __restrict__ col,
    const float* __restrict__ W1, const float* __restrict__ b1v,
    const float* __restrict__ W2, const float* __restrict__ b2v,
    const float* __restrict__ gam, const float* __restrict__ bet,
    u16* __restrict__ h16out, float* __restrict__ f32out)
{
    __shared__ __align__(16) unsigned char lds[49152];
    const int tid = threadIdx.x;
    const int lane = tid & 63;
    const int w = tid >> 6;
    const int rl = lane & 15;
    const int kg = lane >> 4;
    const int tile = blockIdx.x * 64;
    const int r0 = tile + w * 16;

    stage_w(W1, lds, tid);

    // ---- gather phase: wave w aggregates its 16 rows into the z-tile ----
    const u32* hp = h + lane;    // lane = u32 channel
    for (int i = 0; i < 16; ++i) {
        int r = w * 16 + i;              // tile-local row
        int node = tile + r;
        float2 acc = make_float2(0.f, 0.f);
        if (node < NN) {
            acc = h2f2(hp[(size_t)node * 64]);   // self
            int beg = row_ptr[node], end = row_ptr[node + 1];
            for (int j = beg; j < end; j += 8) {
                int n = end - j;               // wave-uniform
                u32 v[8];
                #pragma unroll
                for (int q = 0; q < 8; ++q) {
                    int jj = (q < n) ? j + q : j;   // dup-pad, no OOB
                    v[q] = hp[(size_t)col[jj] * 64];
                }
                #pragma unroll
                for (int q = 0; q < 8; ++q) {
                    if (q < n) { float2 f = h2f2(v[q]); acc.x += f.x; acc.y += f.y; }
                }
            }
        }
        u32 zoff = 32768u + ((((u32)r << 8) + ((u32)lane << 2)) ^ (((u32)r & 7) << 4));
        *(u32*)(lds + zoff) = f22h(acc.x, acc.y);
    }

    // A-frags from own z rows (same-wave LDS ordering; no barrier needed for z)
    f16x8 afr[4];
    {
        int zr = w * 16 + rl;
        #pragma unroll
        for (int kt = 0; kt < 4; ++kt) {
            u32 off = 32768u + ((((u32)zr << 8) + (u32)(kt * 64 + kg * 16)) ^ (((u32)zr & 7) << 4));
            afr[kt] = *(const f16x8*)(lds + off);
        }
    }
    __syncthreads();   // W1 staged (and all z writes globally done)

    // ---- GEMM1 + bias + relu -> hidden buffer (reuses z region, wave-own rows)
    #pragma unroll
    for (int nt = 0; nt < 8; ++nt) {
        f32x4 acc = {0.f, 0.f, 0.f, 0.f};
        int c = nt * 16 + rl;
        #pragma unroll
        for (int kt = 0; kt < 4; ++kt) {
            int kb = kt * 32 + kg * 8;
            u32 off = ((((u32)c << 7) + kb) << 1) ^ (((u32)c & 7) << 4);
            f16x8 b = *(const f16x8*)(lds + off);
            acc = __builtin_amdgcn_mfma_f32_16x16x32_f16(afr[kt], b, acc, 0, 0, 0);
        }
        float bias = b1v[c];
        #pragma unroll
        for (int r = 0; r < 4; ++r) {
            float v = acc[r] + bias;
            v = v > 0.f ? v : 0.f;
            int fullrow = w * 16 + kg * 4 + r;
            u32 hoff = 32768u + (((((u32)fullrow << 7) + c) << 1) ^ (((u32)fullrow & 7) << 4));
            *(u16*)(lds + hoff) = f2h_bits(v);
        }
    }

    __syncthreads();   // all W1 reads done
    stage_w(W2, lds, tid);

    f16x8 afr2[4];
    int hrow = w * 16 + rl;
    #pragma unroll
    for (int kt = 0; kt < 4; ++kt) {
        int kb = kt * 32 + kg * 8;
        u32 off = 32768u + (((((u32)hrow << 7) + kb) << 1) ^ (((u32)hrow & 7) << 4));
        afr2[kt] = *(const f16x8*)(lds + off);
    }
    __syncthreads();   // W2 staged

    // ---- GEMM2 + bias
    f32x4 acc2[8];
    #pragma unroll
    for (int nt = 0; nt < 8; ++nt) {
        f32x4 acc = {0.f, 0.f, 0.f, 0.f};
        int c = nt * 16 + rl;
        #pragma unroll
        for (int kt = 0; kt < 4; ++kt) {
            int kb = kt * 32 + kg * 8;
            u32 off = ((((u32)c << 7) + kb) << 1) ^ (((u32)c & 7) << 4);
            f16x8 b = *(const f16x8*)(lds + off);
            acc = __builtin_amdgcn_mfma_f32_16x16x32_f16(afr2[kt], b, acc, 0, 0, 0);
        }
        float bias = b2v[c];
        acc[0] += bias; acc[1] += bias; acc[2] += bias; acc[3] += bias;
        acc2[nt] = acc;
    }

    // ---- LayerNorm + ReLU + store
    float gamv[8], betv[8];
    #pragma unroll
    for (int nt = 0; nt < 8; ++nt) { gamv[nt] = gam[nt * 16 + rl]; betv[nt] = bet[nt * 16 + rl]; }
    #pragma unroll
    for (int r = 0; r < 4; ++r) {
        float s1 = 0.f, s2 = 0.f;
        #pragma unroll
        for (int nt = 0; nt < 8; ++nt) { float v = acc2[nt][r]; s1 += v; s2 += v * v; }
        #pragma unroll
        for (int m = 1; m < 16; m <<= 1) {
            s1 += __shfl_xor(s1, m, 64);
            s2 += __shfl_xor(s2, m, 64);
        }
        float mu = s1 * (1.f / 128.f);
        float var = s2 * (1.f / 128.f) - mu * mu;
        float rstd = rsqrtf(var + 1e-5f);
        int fullrow = r0 + kg * 4 + r;
        if (fullrow < NN) {
            #pragma unroll
            for (int nt = 0; nt < 8; ++nt) {
                float v = (acc2[nt][r] - mu) * rstd * gamv[nt] + betv[nt];
                v = v > 0.f ? v : 0.f;
                if (h16out) h16out[(size_t)fullrow * 128 + nt * 16 + rl] = f2h_bits(v);
                if (f32out) f32out[(size_t)fullrow * 128 + nt * 16 + rl] = v;
            }
        }
    }
}

// ---------------- host ----------------

extern "C" void kernel_launch(void* const* d_in, const int* in_sizes, int n_in,
                              void* d_out, int out_size, void* d_ws, size_t ws_size,
                              hipStream_t stream) {
    const float* x     = (const float*)d_in[0];
    const int*   ei    = (const int*)d_in[1];
    const float* W1    = (const float*)d_in[2];
    const float* b1    = (const float*)d_in[3];
    const float* W2    = (const float*)d_in[4];
    const float* b2    = (const float*)d_in[5];
    const float* gamma = (const float*)d_in[6];
    const float* beta  = (const float*)d_in[7];
    float* out = (float*)d_out;

    const int* src = ei;
    const int* dst = ei + EE;

    unsigned char* ws = (unsigned char*)d_ws;
    size_t off = 0;
    int* hist_g  = (int*)(ws + off); off += (size_t)NBUCK * NCHUNK * 4;
    int* bbase   = (int*)(ws + off); off += (size_t)(NBUCK + 1) * 4;
    int* row_ptr = (int*)(ws + off); off += (size_t)(NN + 1) * 4; off = (off + 255) & ~(size_t)255;
    u32* rec     = (u32*)(ws + off); off += (size_t)EE * 4;       off = (off + 255) & ~(size_t)255;
    int* colv    = (int*)(ws + off); off += (size_t)EE * 4;       off = (off + 255) & ~(size_t)255;
    u32* h16a    = (u32*)(ws + off); off += (size_t)NN * 64 * 4;
    u32* h16b    = (u32*)(ws + off); off += (size_t)NN * 64 * 4;

    csr_hist<<<NCHUNK, 1024, 0, stream>>>(dst, hist_g);
    csr_scan<<<1, 512, 0, stream>>>(hist_g, bbase);
    csr_scatter<<<NCHUNK, 1024, 0, stream>>>(src, dst, hist_g, rec);
    csr_finalize<<<NBUCK, 256, 0, stream>>>(rec, bbase, row_ptr, colv);
    cvt_kernel<<<(NN * 32 + 255) / 256, 256, 0, stream>>>(x, h16a);

    const u32* hin = h16a;
    u32* hnext = h16b;
    for (int l = 0; l < LL; ++l) {
        layer_kernel<<<(NN + 63) / 64, 256, 0, stream>>>(
            hin, row_ptr, colv,
            W1 + (size_t)l * DD * DD, b1 + l * DD,
            W2 + (size_t)l * DD * DD, b2 + l * DD,
            gamma + l * DD, beta + l * DD,
            (l < LL - 1) ? (u16*)hnext : (u16*)nullptr,
            (l == LL - 1) ? out : (float*)nullptr);
        hin = hnext;
        hnext = (hnext == h16a) ? h16b : h16a;
    }
}

// Round 6
// 342.683 us; speedup vs baseline: 1.7152x; 1.7152x over previous
//
#include <hip/hip_runtime.h>

#define NN 100000
#define EE 1600000
#define DD 128
#define LL 3

typedef float f32x4 __attribute__((ext_vector_type(4)));
typedef _Float16 f16x8 __attribute__((ext_vector_type(8)));
typedef _Float16 f16x2 __attribute__((ext_vector_type(2)));
typedef unsigned short u16;
typedef unsigned int u32;
typedef u16 u16x8 __attribute__((ext_vector_type(8)));

// CSR-build geometry: buckets of 256 nodes, chunks of 16384 edges
#define NBUCK ((NN + 255) / 256)          // 391
#define CHUNK 16384
#define NCHUNK ((EE + CHUNK - 1) / CHUNK) // 98
#define PADMAX 1792                        // 256 nodes * 7 max pad per bucket

__device__ __forceinline__ u16 f2h_bits(float f) {
    _Float16 h = (_Float16)f;
    return __builtin_bit_cast(u16, h);
}
__device__ __forceinline__ f16x2 bc16x2(u32 v) {
    return __builtin_bit_cast(f16x2, v);
}
__device__ __forceinline__ u32 f22h(float x, float y) {
    return (u32)f2h_bits(x) | ((u32)f2h_bits(y) << 16);
}

// ---------------- CSR build: bucketed counting sort by dst ----------------

__global__ __launch_bounds__(1024) void csr_hist(const int* __restrict__ dst,
                                                 int* __restrict__ hist_g) {
    __shared__ int h[NBUCK];
    int t = threadIdx.x, c = blockIdx.x;
    for (int i = t; i < NBUCK; i += 1024) h[i] = 0;
    __syncthreads();
    int base = c * CHUNK;
    #pragma unroll
    for (int i = 0; i < CHUNK / 1024; ++i) {
        int e = base + t + i * 1024;
        if (e < EE) atomicAdd(&h[dst[e] >> 8], 1);
    }
    __syncthreads();
    for (int i = t; i < NBUCK; i += 1024) hist_g[i * NCHUNK + c] = h[i];
}

__global__ __launch_bounds__(512) void csr_scan(int* __restrict__ hist_g,
                                                int* __restrict__ bbase) {
    __shared__ int tot[512];
    int t = threadIdx.x;
    int sum = 0;
    if (t < NBUCK) {
        int* p = hist_g + t * NCHUNK;
        for (int c = 0; c < NCHUNK; ++c) { int v = p[c]; p[c] = sum; sum += v; }
    }
    tot[t] = sum; __syncthreads();
    for (int off = 1; off < 512; off <<= 1) {
        int u = (t >= off) ? tot[t - off] : 0;
        __syncthreads();
        tot[t] += u;
        __syncthreads();
    }
    int base = tot[t] - sum;   // exclusive
    if (t < NBUCK) {
        bbase[t] = base;
        int* p = hist_g + t * NCHUNK;
        for (int c = 0; c < NCHUNK; ++c) p[c] += base;
    }
    if (t == 0) bbase[NBUCK] = EE;
}

__global__ __launch_bounds__(1024) void csr_scatter(const int* __restrict__ src,
                                                    const int* __restrict__ dst,
                                                    const int* __restrict__ hist_g,
                                                    u32* __restrict__ rec) {
    __shared__ int cur[NBUCK];
    int t = threadIdx.x, c = blockIdx.x;
    for (int i = t; i < NBUCK; i += 1024) cur[i] = hist_g[i * NCHUNK + c];
    __syncthreads();
    int base = c * CHUNK;
    #pragma unroll
    for (int i = 0; i < CHUNK / 1024; ++i) {
        int e = base + t + i * 1024;
        if (e < EE) {
            int d = dst[e];
            int slot = atomicAdd(&cur[d >> 8], 1);
            rec[slot] = (u32)src[e] | ((u32)(d & 255) << 17);
        }
    }
}

// one block per bucket: padded (multiple-of-8) per-node segments, pad -> node NN
__global__ __launch_bounds__(256) void csr_finalize(const u32* __restrict__ rec,
                                                    const int* __restrict__ bbase,
                                                    int* __restrict__ rbeg,
                                                    int* __restrict__ rpend,
                                                    int* __restrict__ col) {
    __shared__ int cur[256];
    __shared__ int sc[256];
    int b = blockIdx.x, t = threadIdx.x;
    int base = bbase[b], tot = bbase[b + 1] - base;
    int pbase = base + b * PADMAX;
    sc[t] = 0; __syncthreads();
    for (int r = t; r < tot; r += 256) atomicAdd(&sc[rec[base + r] >> 17], 1);
    __syncthreads();
    int cnt = sc[t];
    int pcnt = (cnt + 7) & ~7;
    // inclusive scan of pcnt
    sc[t] = pcnt; __syncthreads();
    for (int off = 1; off < 256; off <<= 1) {
        int u = (t >= off) ? sc[t - off] : 0;
        __syncthreads();
        sc[t] += u;
        __syncthreads();
    }
    int mybeg = pbase + sc[t] - pcnt;
    cur[t] = mybeg;
    int nid = b * 256 + t;
    if (nid < NN) { rbeg[nid] = mybeg; rpend[nid] = mybeg + pcnt; }
    // fill padding with NN (zero row)
    for (int k = cnt; k < pcnt; ++k) col[mybeg + k] = NN;
    __syncthreads();
    for (int r = t; r < tot; r += 256) {
        u32 rc = rec[base + r];
        int slot = atomicAdd(&cur[rc >> 17], 1);
        col[slot] = (int)(rc & 0x1FFFFu);
    }
}

// ---------------- x (fp32) -> h16 ----------------

__global__ void cvt_kernel(const float* __restrict__ x, u32* __restrict__ h) {
    int i = blockIdx.x * blockDim.x + threadIdx.x;
    if (i < NN * 32) {
        float4 v = ((const float4*)x)[i];
        h[i * 2]     = f22h(v.x, v.y);
        h[i * 2 + 1] = f22h(v.z, v.w);
    }
}

// ---------------- aggregation: z16 = h16 + sum_{j in N(i)} h16[j] ----------------
// one wave per node; lane c holds halves [2c,2c+1]; padded lists: 8 unconditional
// gathers per iter, fp16 pairwise-tree partial sum, fp32 master accumulator.

__global__ __launch_bounds__(256) void agg16_kernel(
    const u32* __restrict__ h, const int* __restrict__ rbeg,
    const int* __restrict__ rpend, const int* __restrict__ col,
    u32* __restrict__ z) {
    int node = blockIdx.x * 4 + (threadIdx.x >> 6);
    int c = threadIdx.x & 63;
    const u32* hp = h + c;
    f16x2 self = bc16x2(hp[(size_t)node * 64]);
    float accx = (float)self[0], accy = (float)self[1];
    int beg = rbeg[node], end = rpend[node];
    for (int j = beg; j < end; j += 8) {
        u32 v[8];
        #pragma unroll
        for (int q = 0; q < 8; ++q) v[q] = hp[(size_t)col[j + q] * 64];
        f16x2 s0 = bc16x2(v[0]) + bc16x2(v[1]);
        f16x2 s1 = bc16x2(v[2]) + bc16x2(v[3]);
        f16x2 s2 = bc16x2(v[4]) + bc16x2(v[5]);
        f16x2 s3 = bc16x2(v[6]) + bc16x2(v[7]);
        s0 = s0 + s1; s2 = s2 + s3; s0 = s0 + s2;
        accx += (float)s0[0]; accy += (float)s0[1];
    }
    z[(size_t)node * 64 + c] = f22h(accx, accy);
}

// ---------------- fused MLP + LayerNorm + ReLU ----------------

__device__ __forceinline__ void stage_w(const float* __restrict__ W, unsigned char* lds, int tid) {
    #pragma unroll
    for (int i = 0; i < 8; ++i) {
        int p = tid + i * 256;
        int c = p & 127;
        int k0 = (p >> 7) << 3;
        u16x8 t;
        #pragma unroll
        for (int j = 0; j < 8; ++j) t[j] = f2h_bits(W[(k0 + j) * 128 + c]);
        u32 off = ((((u32)c << 7) + k0) << 1) ^ (((u32)c & 7) << 4);
        *(u16x8*)(lds + off) = t;
    }
}

__global__ __launch_bounds__(256) void mlp_kernel(
    const u16* __restrict__ z16, const float* __restrict__ W1,
    const float* __restrict__ b1v, const float* __restrict__ W2,
    const float* __restrict__ b2v, const float* __restrict__ gam,
    const float* __restrict__ bet, u16* __restrict__ h16out,
    float* __restrict__ f32out)
{
    __shared__ __align__(16) unsigned char lds[49152];
    const int tid = threadIdx.x;
    const int lane = tid & 63;
    const int w = tid >> 6;
    const int rl = lane & 15;
    const int kg = lane >> 4;
    const int tile = blockIdx.x * 64;
    const int r0 = tile + w * 16;

    stage_w(W1, lds, tid);

    int zrow = r0 + rl; if (zrow > NN - 1) zrow = NN - 1;
    const u16* zp = z16 + (size_t)zrow * 128;
    f16x8 afr[4];
    #pragma unroll
    for (int kt = 0; kt < 4; ++kt)
        afr[kt] = *(const f16x8*)(zp + kt * 32 + kg * 8);
    __syncthreads();   // W1 staged

    #pragma unroll
    for (int nt = 0; nt < 8; ++nt) {
        f32x4 acc = {0.f, 0.f, 0.f, 0.f};
        int c = nt * 16 + rl;
        #pragma unroll
        for (int kt = 0; kt < 4; ++kt) {
            int kb = kt * 32 + kg * 8;
            u32 off = ((((u32)c << 7) + kb) << 1) ^ (((u32)c & 7) << 4);
            f16x8 b = *(const f16x8*)(lds + off);
            acc = __builtin_amdgcn_mfma_f32_16x16x32_f16(afr[kt], b, acc, 0, 0, 0);
        }
        float bias = b1v[c];
        #pragma unroll
        for (int r = 0; r < 4; ++r) {
            float v = acc[r] + bias;
            v = v > 0.f ? v : 0.f;
            int fullrow = w * 16 + kg * 4 + r;
            u32 hoff = 32768u + (((((u32)fullrow << 7) + c) << 1) ^ (((u32)fullrow & 7) << 4));
            *(u16*)(lds + hoff) = f2h_bits(v);
        }
    }

    __syncthreads();
    stage_w(W2, lds, tid);

    f16x8 afr2[4];
    int hrow = w * 16 + rl;
    #pragma unroll
    for (int kt = 0; kt < 4; ++kt) {
        int kb = kt * 32 + kg * 8;
        u32 off = 32768u + (((((u32)hrow << 7) + kb) << 1) ^ (((u32)hrow & 7) << 4));
        afr2[kt] = *(const f16x8*)(lds + off);
    }
    __syncthreads();

    f32x4 acc2[8];
    #pragma unroll
    for (int nt = 0; nt < 8; ++nt) {
        f32x4 acc = {0.f, 0.f, 0.f, 0.f};
        int c = nt * 16 + rl;
        #pragma unroll
        for (int kt = 0; kt < 4; ++kt) {
            int kb = kt * 32 + kg * 8;
            u32 off = ((((u32)c << 7) + kb) << 1) ^ (((u32)c & 7) << 4);
            f16x8 b = *(const f16x8*)(lds + off);
            acc = __builtin_amdgcn_mfma_f32_16x16x32_f16(afr2[kt], b, acc, 0, 0, 0);
        }
        float bias = b2v[c];
        acc[0] += bias; acc[1] += bias; acc[2] += bias; acc[3] += bias;
        acc2[nt] = acc;
    }

    float gamv[8], betv[8];
    #pragma unroll
    for (int nt = 0; nt < 8; ++nt) { gamv[nt] = gam[nt * 16 + rl]; betv[nt] = bet[nt * 16 + rl]; }
    #pragma unroll
    for (int r = 0; r < 4; ++r) {
        float s1 = 0.f, s2 = 0.f;
        #pragma unroll
        for (int nt = 0; nt < 8; ++nt) { float v = acc2[nt][r]; s1 += v; s2 += v * v; }
        #pragma unroll
        for (int m = 1; m < 16; m <<= 1) {
            s1 += __shfl_xor(s1, m, 64);
            s2 += __shfl_xor(s2, m, 64);
        }
        float mu = s1 * (1.f / 128.f);
        float var = s2 * (1.f / 128.f) - mu * mu;
        float rstd = rsqrtf(var + 1e-5f);
        int fullrow = r0 + kg * 4 + r;
        if (fullrow < NN) {
            #pragma unroll
            for (int nt = 0; nt < 8; ++nt) {
                float v = (acc2[nt][r] - mu) * rstd * gamv[nt] + betv[nt];
                v = v > 0.f ? v : 0.f;
                if (h16out) h16out[(size_t)fullrow * 128 + nt * 16 + rl] = f2h_bits(v);
                if (f32out) f32out[(size_t)fullrow * 128 + nt * 16 + rl] = v;
            }
        }
    }
}

// ---------------- host ----------------

extern "C" void kernel_launch(void* const* d_in, const int* in_sizes, int n_in,
                              void* d_out, int out_size, void* d_ws, size_t ws_size,
                              hipStream_t stream) {
    const float* x     = (const float*)d_in[0];
    const int*   ei    = (const int*)d_in[1];
    const float* W1    = (const float*)d_in[2];
    const float* b1    = (const float*)d_in[3];
    const float* W2    = (const float*)d_in[4];
    const float* b2    = (const float*)d_in[5];
    const float* gamma = (const float*)d_in[6];
    const float* beta  = (const float*)d_in[7];
    float* out = (float*)d_out;

    const int* src = ei;
    const int* dst = ei + EE;

    unsigned char* ws = (unsigned char*)d_ws;
    size_t off = 0;
    int* hist_g  = (int*)(ws + off); off += (size_t)NBUCK * NCHUNK * 4;
    int* bbase   = (int*)(ws + off); off += (size_t)(NBUCK + 1) * 4;
    int* rbeg    = (int*)(ws + off); off += (size_t)NN * 4;
    int* rpend   = (int*)(ws + off); off += (size_t)NN * 4; off = (off + 255) & ~(size_t)255;
    u32* rec     = (u32*)(ws + off); off += (size_t)EE * 4; off = (off + 255) & ~(size_t)255;
    int* colv    = (int*)(ws + off); off += ((size_t)EE + (size_t)NBUCK * PADMAX + 64) * 4;
    off = (off + 255) & ~(size_t)255;
    u32* h16a    = (u32*)(ws + off); off += (size_t)(NN + 1) * 64 * 4;
    u32* h16b    = (u32*)(ws + off); off += (size_t)(NN + 1) * 64 * 4;
    u32* z16     = (u32*)(ws + off); off += (size_t)NN * 64 * 4;

    csr_hist<<<NCHUNK, 1024, 0, stream>>>(dst, hist_g);
    csr_scan<<<1, 512, 0, stream>>>(hist_g, bbase);
    csr_scatter<<<NCHUNK, 1024, 0, stream>>>(src, dst, hist_g, rec);
    csr_finalize<<<NBUCK, 256, 0, stream>>>(rec, bbase, rbeg, rpend, colv);
    cvt_kernel<<<(NN * 32 + 255) / 256, 256, 0, stream>>>(x, h16a);
    // zero row NN of both h16 buffers (padding gathers land here)
    hipMemsetAsync(h16a + (size_t)NN * 64, 0, 256, stream);
    hipMemsetAsync(h16b + (size_t)NN * 64, 0, 256, stream);

    const u32* hin = h16a;
    u32* hnext = h16b;
    for (int l = 0; l < LL; ++l) {
        agg16_kernel<<<NN / 4, 256, 0, stream>>>(hin, rbeg, rpend, colv, z16);
        mlp_kernel<<<(NN + 63) / 64, 256, 0, stream>>>(
            (const u16*)z16, W1 + (size_t)l * DD * DD, b1 + l * DD,
            W2 + (size_t)l * DD * DD, b2 + l * DD,
            gamma + l * DD, beta + l * DD,
            (l < LL - 1) ? (u16*)hnext : (u16*)nullptr,
            (l == LL - 1) ? out : (float*)nullptr);
        hin = hnext;
        hnext = (hnext == h16a) ? h16b : h16a;
    }
}